// Round 5
// baseline (203.519 us; speedup 1.0000x reference)
//
#include <hip/hip_runtime.h>

#define SEQ   200
#define BATCH 1024
#define DIM   300
#define HID   600
#define VOCAB 100000
#define JC    4            // j-chunks across blockIdx.y (mlp)
#define JPER  (HID / JC)   // 150 j per chunk
#define JT    10           // j-tile

#define PACKED_BYTES ((size_t)VOCAB * HID * 2)   // 120,000,000
#define HIDDEN_BYTES ((size_t)BATCH * HID * 4)   // 2,457,600

// ---------- bf16 helpers ----------
__device__ __forceinline__ unsigned int f2bf(float f) {
  const unsigned int u = __float_as_uint(f);
  return (u + 0x7FFFu + ((u >> 16) & 1u)) >> 16;   // RNE
}

// ---------- Kernel 0: fuse+convert tables to packed bf16 [VOCAB][600] ----
// Thread = one 16B output slot (8 bf16). Writes perfectly linear; reads are
// two aligned float4 from lut/slut (slot 37 straddles the concat boundary).
__global__ __launch_bounds__(256) void convert_kernel(
    const float* __restrict__ lut,
    const float* __restrict__ slut,
    uint4* __restrict__ packed) {
  const unsigned int o = blockIdx.x * 256u + threadIdx.x;
  if (o >= (unsigned int)VOCAB * 75u) return;
  const unsigned int v = o / 75u, c8 = o % 75u;
  const float* lrow = lut  + (size_t)v * DIM;
  const float* srow = slut + (size_t)v * DIM;
  const float *p0, *p1;
  if (c8 < 37u)       { p0 = lrow + 8u * c8;         p1 = p0 + 4; }
  else if (c8 == 37u) { p0 = lrow + 296;             p1 = srow;   }
  else                { p0 = srow + 8u * c8 - 300u;  p1 = p0 + 4; }
  const float4 a = *(const float4*)p0;
  const float4 b = *(const float4*)p1;
  uint4 r;
  r.x = f2bf(a.x) | (f2bf(a.y) << 16);
  r.y = f2bf(a.z) | (f2bf(a.w) << 16);
  r.z = f2bf(b.x) | (f2bf(b.y) << 16);
  r.w = f2bf(b.z) | (f2bf(b.w) << 16);
  packed[o] = r;
}

// ---------- Kernel 1 (fast): dedup + fused bf16 row-gather ---------------
// One block per column. tid>>7 = s-half (2 groups x 100 rows), slot=tid&127
// (<75 active): 16B bf16x8 slice of the 1200B packed row. LDS-combine.
__global__ __launch_bounds__(256) void embed_bf16_kernel(
    const int* __restrict__ tokens,
    const ushort* __restrict__ packed,
    float* __restrict__ hidden) {
  const int b = blockIdx.x;
  const int tid = threadIdx.x;

  __shared__ int   toks[SEQ];
  __shared__ float keep[SEQ];
  __shared__ float accs[2][75][8];   // 4.8 KB

  for (int s = tid; s < SEQ; s += 256) toks[s] = tokens[s * BATCH + b];
  __syncthreads();

  for (int s = tid; s < SEQ; s += 256) {
    const int t = toks[s];
    float m = 1.f;
    for (int p = 0; p < s; ++p) {
      if (toks[p] == t) { m = 0.f; break; }
    }
    keep[s] = m;
  }
  __syncthreads();

  const int grp  = tid >> 7;    // s-half
  const int slot = tid & 127;
  if (slot < 75) {
    float acc[8] = {0.f, 0.f, 0.f, 0.f, 0.f, 0.f, 0.f, 0.f};
    const int s0 = grp * 100, s1 = s0 + 100;
#pragma unroll 4
    for (int s = s0; s < s1; ++s) {
      const float m = keep[s];
      const uint4 u = *(const uint4*)(packed + (size_t)toks[s] * HID + slot * 8);
      acc[0] += m * __uint_as_float(u.x << 16);
      acc[1] += m * __uint_as_float(u.x & 0xFFFF0000u);
      acc[2] += m * __uint_as_float(u.y << 16);
      acc[3] += m * __uint_as_float(u.y & 0xFFFF0000u);
      acc[4] += m * __uint_as_float(u.z << 16);
      acc[5] += m * __uint_as_float(u.z & 0xFFFF0000u);
      acc[6] += m * __uint_as_float(u.w << 16);
      acc[7] += m * __uint_as_float(u.w & 0xFFFF0000u);
    }
#pragma unroll
    for (int q = 0; q < 8; ++q) accs[grp][slot][q] = acc[q];
  }
  __syncthreads();

  if (tid < 75) {
    float4 o0, o1;
    o0.x = accs[0][tid][0] + accs[1][tid][0];
    o0.y = accs[0][tid][1] + accs[1][tid][1];
    o0.z = accs[0][tid][2] + accs[1][tid][2];
    o0.w = accs[0][tid][3] + accs[1][tid][3];
    o1.x = accs[0][tid][4] + accs[1][tid][4];
    o1.y = accs[0][tid][5] + accs[1][tid][5];
    o1.z = accs[0][tid][6] + accs[1][tid][6];
    o1.w = accs[0][tid][7] + accs[1][tid][7];
    float* hb = hidden + (size_t)b * HID + tid * 8;
    *(float4*)hb       = o0;
    *((float4*)hb + 1) = o1;
  }
}

// ---------- Kernel 1 (fallback, fp32 direct gather — round-4 proven) -----
__global__ __launch_bounds__(256) void embed_kernel(
    const int* __restrict__ tokens,
    const float* __restrict__ lut,
    const float* __restrict__ slut,
    float* __restrict__ hidden) {
  const int b = blockIdx.x;
  const int tid = threadIdx.x;

  __shared__ int   toks[SEQ];
  __shared__ float keep[SEQ];

  for (int s = tid; s < SEQ; s += 256) toks[s] = tokens[s * BATCH + b];
  __syncthreads();

  for (int s = tid; s < SEQ; s += 256) {
    const int t = toks[s];
    float m = 1.f;
    for (int p = 0; p < s; ++p) {
      if (toks[p] == t) { m = 0.f; break; }
    }
    keep[s] = m;
  }
  __syncthreads();

  const int grp  = tid >> 7;
  const int slot = tid & 127;
  if (slot < DIM / 4) {
    const float* __restrict__ tab = grp ? slut : lut;
    float4 a = make_float4(0.f, 0.f, 0.f, 0.f);
#pragma unroll 8
    for (int s = 0; s < SEQ; ++s) {
      const float  m = keep[s];
      const float4 v = ((const float4*)(tab + (size_t)toks[s] * DIM))[slot];
      a.x += m * v.x; a.y += m * v.y; a.z += m * v.z; a.w += m * v.w;
    }
    float* hb = hidden + (size_t)b * HID + grp * DIM;
    ((float4*)hb)[slot] = a;
  }
}

// ---------- Kernel 2a: out[b] = b2 ---------------------------------------
__global__ __launch_bounds__(256) void out_init_kernel(
    float* __restrict__ out, const float* __restrict__ b2) {
  const int i = blockIdx.x * 256 + threadIdx.x;
  if (i < BATCH) out[i] = b2[0];
}

// ---------- Kernel 2b: MLP, zero-LDS wave-dot + DPP reduce ---------------
template <int CTRL>
__device__ __forceinline__ float dpp_add(float x) {
  const int y = __builtin_amdgcn_update_dpp(
      0, __float_as_int(x), CTRL, 0xf, 0xf, true);
  return x + __int_as_float(y);
}

__global__ __launch_bounds__(256) void mlp_kernel(
    const float* __restrict__ hidden,
    const float* __restrict__ W1,
    const float* __restrict__ b1,
    const float* __restrict__ W2,
    float* __restrict__ out) {
  const int wave = threadIdx.x >> 6;
  const int lane = threadIdx.x & 63;
  const int b    = blockIdx.x * 4 + wave;
  const int j0   = blockIdx.y * JPER;

  float a[10];
  const float* __restrict__ hb = hidden + (size_t)b * HID;
#pragma unroll
  for (int i = 0; i < 9; ++i) a[i] = hb[lane + 64 * i];
  a[9] = (lane < 24) ? hb[lane + 576] : 0.f;

  float acc = 0.f;

  for (int jg = 0; jg < JPER; jg += JT) {
    float dot[JT];
#pragma unroll
    for (int jj = 0; jj < JT; ++jj) dot[jj] = 0.f;

#pragma unroll
    for (int jj = 0; jj < JT; ++jj) {
      const float* __restrict__ wr = W1 + (size_t)(j0 + jg + jj) * HID;
#pragma unroll
      for (int i = 0; i < 9; ++i) dot[jj] += a[i] * wr[lane + 64 * i];
      dot[jj] += (lane < 24) ? a[9] * wr[lane + 576] : 0.f;
    }

#pragma unroll
    for (int jj = 0; jj < JT; ++jj) {
      float h = dot[jj];
      h = dpp_add<0x111>(h);   // row_shr:1
      h = dpp_add<0x112>(h);   // row_shr:2
      h = dpp_add<0x114>(h);   // row_shr:4
      h = dpp_add<0x118>(h);   // row_shr:8
      h = dpp_add<0x142>(h);   // row_bcast:15
      h = dpp_add<0x143>(h);   // row_bcast:31  -> lane 63 = full sum
      const int j = j0 + jg + jj;
      const float r = fmaxf(h + b1[j], 0.f) * W2[j];
      if (lane == 63) acc += r;
    }
  }

  if (lane == 63) atomicAdd(&out[b], acc);
}

extern "C" void kernel_launch(void* const* d_in, const int* in_sizes, int n_in,
                              void* d_out, int out_size, void* d_ws, size_t ws_size,
                              hipStream_t stream) {
  const int*   tokens = (const int*)  d_in[0];
  const float* lut    = (const float*)d_in[1];
  const float* slut   = (const float*)d_in[2];
  const float* W1     = (const float*)d_in[3];
  const float* b1     = (const float*)d_in[4];
  const float* W2     = (const float*)d_in[5];
  const float* b2     = (const float*)d_in[6];
  float* out = (float*)d_out;

  out_init_kernel<<<(BATCH + 255) / 256, 256, 0, stream>>>(out, b2);

  if (ws_size >= PACKED_BYTES + HIDDEN_BYTES) {
    // fast path: packed bf16 table at ws[0], hidden fp32 after it
    ushort* packed = (ushort*)d_ws;
    float*  hidden = (float*)((char*)d_ws + PACKED_BYTES);
    const unsigned int nslots = (unsigned int)VOCAB * 75u;
    convert_kernel<<<(nslots + 255) / 256, 256, 0, stream>>>(
        lut, slut, (uint4*)packed);
    embed_bf16_kernel<<<BATCH, 256, 0, stream>>>(tokens, packed, hidden);
    mlp_kernel<<<dim3(BATCH / 4, JC), 256, 0, stream>>>(hidden, W1, b1, W2, out);
  } else {
    // fallback: fp32 direct gather
    float* hidden = (float*)d_ws;
    embed_kernel<<<BATCH, 256, 0, stream>>>(tokens, lut, slut, hidden);
    mlp_kernel<<<dim3(BATCH / 4, JC), 256, 0, stream>>>(hidden, W1, b1, W2, out);
  }
}

// Round 6
// 145.522 us; speedup vs baseline: 1.3985x; 1.3985x over previous
//
#include <hip/hip_runtime.h>

#define SEQ   200
#define BATCH 1024
#define DIM   300
#define HID   600
#define VOCAB 100000

#define BW    4            // batches per wave (mlp)
#define JCH   12           // j-chunks across blockIdx.y (mlp)
#define JPER  (HID / JCH)  // 50 j per chunk

#define PACKED_BYTES ((size_t)VOCAB * HID * 2)   // 120,000,000
#define HIDDEN_BYTES ((size_t)BATCH * HID * 4)   // 2,457,600

// ---------- bf16 helpers ----------
__device__ __forceinline__ unsigned int f2bf(float f) {
  const unsigned int u = __float_as_uint(f);
  return (u + 0x7FFFu + ((u >> 16) & 1u)) >> 16;   // RNE
}

// ---------- Kernel 0: fuse+convert tables to packed bf16 [VOCAB][600] ----
// Thread = one 16B output slot (8 bf16). Writes perfectly linear; reads are
// two aligned float4 from lut/slut (slot 37 straddles the concat boundary).
__global__ __launch_bounds__(256) void convert_kernel(
    const float* __restrict__ lut,
    const float* __restrict__ slut,
    uint4* __restrict__ packed) {
  const unsigned int o = blockIdx.x * 256u + threadIdx.x;
  if (o >= (unsigned int)VOCAB * 75u) return;
  const unsigned int v = o / 75u, c8 = o % 75u;
  const float* lrow = lut  + (size_t)v * DIM;
  const float* srow = slut + (size_t)v * DIM;
  const float *p0, *p1;
  if (c8 < 37u)       { p0 = lrow + 8u * c8;         p1 = p0 + 4; }
  else if (c8 == 37u) { p0 = lrow + 296;             p1 = srow;   }
  else                { p0 = srow + 8u * c8 - 300u;  p1 = p0 + 4; }
  const float4 a = *(const float4*)p0;
  const float4 b = *(const float4*)p1;
  uint4 r;
  r.x = f2bf(a.x) | (f2bf(a.y) << 16);
  r.y = f2bf(a.z) | (f2bf(a.w) << 16);
  r.z = f2bf(b.x) | (f2bf(b.y) << 16);
  r.w = f2bf(b.z) | (f2bf(b.w) << 16);
  packed[o] = r;
}

// ---------- Kernel 1: dedup + fused bf16 row-gather ----------------------
// One block per column. 3 s-groups x 75 lanes (225 active): grp g covers
// ~67 sequence slots; slot = 16B bf16x8 slice of the 1200B packed row.
__global__ __launch_bounds__(256) void embed_bf16_kernel(
    const int* __restrict__ tokens,
    const ushort* __restrict__ packed,
    float* __restrict__ hidden) {
  const int b = blockIdx.x;
  const int tid = threadIdx.x;

  __shared__ int   toks[SEQ];
  __shared__ float keep[SEQ];
  __shared__ float accs[3][75][8];   // 7.2 KB

  for (int s = tid; s < SEQ; s += 256) toks[s] = tokens[s * BATCH + b];
  __syncthreads();

  for (int s = tid; s < SEQ; s += 256) {
    const int t = toks[s];
    float m = 1.f;
    for (int p = 0; p < s; ++p) {
      if (toks[p] == t) { m = 0.f; break; }
    }
    keep[s] = m;
  }
  __syncthreads();

  const int grp  = tid / 75;    // 0,1,2 active; tid 225..255 idle
  const int slot = tid % 75;
  if (grp < 3) {
    float acc[8] = {0.f, 0.f, 0.f, 0.f, 0.f, 0.f, 0.f, 0.f};
    const int s0 = grp * 67;
    const int s1 = (grp == 2) ? SEQ : s0 + 67;
#pragma unroll 4
    for (int s = s0; s < s1; ++s) {
      const float m = keep[s];
      const uint4 u = *(const uint4*)(packed + (size_t)toks[s] * HID + slot * 8);
      acc[0] += m * __uint_as_float(u.x << 16);
      acc[1] += m * __uint_as_float(u.x & 0xFFFF0000u);
      acc[2] += m * __uint_as_float(u.y << 16);
      acc[3] += m * __uint_as_float(u.y & 0xFFFF0000u);
      acc[4] += m * __uint_as_float(u.z << 16);
      acc[5] += m * __uint_as_float(u.z & 0xFFFF0000u);
      acc[6] += m * __uint_as_float(u.w << 16);
      acc[7] += m * __uint_as_float(u.w & 0xFFFF0000u);
    }
#pragma unroll
    for (int q = 0; q < 8; ++q) accs[grp][slot][q] = acc[q];
  }
  __syncthreads();

  if (tid < 75) {
    float4 o0, o1;
    o0.x = accs[0][tid][0] + accs[1][tid][0] + accs[2][tid][0];
    o0.y = accs[0][tid][1] + accs[1][tid][1] + accs[2][tid][1];
    o0.z = accs[0][tid][2] + accs[1][tid][2] + accs[2][tid][2];
    o0.w = accs[0][tid][3] + accs[1][tid][3] + accs[2][tid][3];
    o1.x = accs[0][tid][4] + accs[1][tid][4] + accs[2][tid][4];
    o1.y = accs[0][tid][5] + accs[1][tid][5] + accs[2][tid][5];
    o1.z = accs[0][tid][6] + accs[1][tid][6] + accs[2][tid][6];
    o1.w = accs[0][tid][7] + accs[1][tid][7] + accs[2][tid][7];
    float* hb = hidden + (size_t)b * HID + tid * 8;
    *(float4*)hb       = o0;
    *((float4*)hb + 1) = o1;
  }
}

// ---------- Kernel 2a: out[b] = b2 ---------------------------------------
__global__ __launch_bounds__(256) void out_init_kernel(
    float* __restrict__ out, const float* __restrict__ b2) {
  const int i = blockIdx.x * 256 + threadIdx.x;
  if (i < BATCH) out[i] = b2[0];
}

// ---------- Kernel 2b: MLP — 4 batches/wave, W1 reused 4x, DPP reduce ----
// Wave = 4 batch rows (hidden in 40 VGPRs); lanes split k. Each W1 element
// loaded once per wave feeds 4 FMAs -> W1 L2 traffic 368 MB (was 1.47 GB).
// Grid: 64 batch-groups x 12 j-chunks = 768 blocks.
template <int CTRL>
__device__ __forceinline__ float dpp_add(float x) {
  const int y = __builtin_amdgcn_update_dpp(
      0, __float_as_int(x), CTRL, 0xf, 0xf, true);
  return x + __int_as_float(y);
}

__device__ __forceinline__ float wave_sum(float h) {
  h = dpp_add<0x111>(h);   // row_shr:1
  h = dpp_add<0x112>(h);   // row_shr:2
  h = dpp_add<0x114>(h);   // row_shr:4
  h = dpp_add<0x118>(h);   // row_shr:8
  h = dpp_add<0x142>(h);   // row_bcast:15
  h = dpp_add<0x143>(h);   // row_bcast:31  -> lane 63 holds full sum
  return h;
}

__global__ __launch_bounds__(256) void mlp_kernel(
    const float* __restrict__ hidden,
    const float* __restrict__ W1,
    const float* __restrict__ b1,
    const float* __restrict__ W2,
    float* __restrict__ out) {
  const int wave = threadIdx.x >> 6;
  const int lane = threadIdx.x & 63;
  const int b0   = (blockIdx.x * 4 + wave) * BW;
  const int j0   = blockIdx.y * JPER;

  // preload 4 hidden rows: k = lane + 64*i (600 = 64*9 + 24)
  float a[BW][10];
#pragma unroll
  for (int bb = 0; bb < BW; ++bb) {
    const float* __restrict__ hb = hidden + (size_t)(b0 + bb) * HID;
#pragma unroll
    for (int i = 0; i < 9; ++i) a[bb][i] = hb[lane + 64 * i];
    a[bb][9] = (lane < 24) ? hb[lane + 576] : 0.f;
  }

  float acc[BW] = {0.f, 0.f, 0.f, 0.f};

#pragma unroll 2
  for (int jj = 0; jj < JPER; ++jj) {
    const int j = j0 + jj;
    const float* __restrict__ wr = W1 + (size_t)j * HID;
    float d0 = 0.f, d1 = 0.f, d2 = 0.f, d3 = 0.f;
#pragma unroll
    for (int i = 0; i < 9; ++i) {
      const float w = wr[lane + 64 * i];
      d0 += a[0][i] * w;
      d1 += a[1][i] * w;
      d2 += a[2][i] * w;
      d3 += a[3][i] * w;
    }
    {
      const float w = (lane < 24) ? wr[lane + 576] : 0.f;
      d0 += a[0][9] * w;
      d1 += a[1][9] * w;
      d2 += a[2][9] * w;
      d3 += a[3][9] * w;
    }
    // 4 independent 6-step DPP chains (ILP hides DPP latency)
    d0 = wave_sum(d0); d1 = wave_sum(d1);
    d2 = wave_sum(d2); d3 = wave_sum(d3);
    // branch-free epilogue: only lane 63's acc is ever consumed
    const float b1j = b1[j];
    const float w2j = W2[j];
    acc[0] += fmaxf(d0 + b1j, 0.f) * w2j;
    acc[1] += fmaxf(d1 + b1j, 0.f) * w2j;
    acc[2] += fmaxf(d2 + b1j, 0.f) * w2j;
    acc[3] += fmaxf(d3 + b1j, 0.f) * w2j;
  }

  if (lane == 63) {
#pragma unroll
    for (int bb = 0; bb < BW; ++bb) atomicAdd(&out[b0 + bb], acc[bb]);
  }
}

extern "C" void kernel_launch(void* const* d_in, const int* in_sizes, int n_in,
                              void* d_out, int out_size, void* d_ws, size_t ws_size,
                              hipStream_t stream) {
  const int*   tokens = (const int*)  d_in[0];
  const float* lut    = (const float*)d_in[1];
  const float* slut   = (const float*)d_in[2];
  const float* W1     = (const float*)d_in[3];
  const float* b1     = (const float*)d_in[4];
  const float* W2     = (const float*)d_in[5];
  const float* b2     = (const float*)d_in[6];
  float* out = (float*)d_out;

  ushort* packed = (ushort*)d_ws;
  float*  hidden = (float*)((char*)d_ws + PACKED_BYTES);

  out_init_kernel<<<(BATCH + 255) / 256, 256, 0, stream>>>(out, b2);
  const unsigned int nslots = (unsigned int)VOCAB * 75u;
  convert_kernel<<<(nslots + 255) / 256, 256, 0, stream>>>(
      lut, slut, (uint4*)packed);
  embed_bf16_kernel<<<BATCH, 256, 0, stream>>>(tokens, packed, hidden);
  mlp_kernel<<<dim3(BATCH / (4 * BW), JCH), 256, 0, stream>>>(
      hidden, W1, b1, W2, out);
}